// Round 1
// 275.225 us; speedup vs baseline: 1.1459x; 1.1459x over previous
//
#include <hip/hip_runtime.h>

static constexpr int FIN = 128;
static constexpr int HD  = 64;
static constexpr int CD  = 40;

typedef __attribute__((ext_vector_type(8))) short short8;   // 8 bf16 = 4 VGPR
typedef __attribute__((ext_vector_type(4))) float f32x4;    // MFMA acc

__device__ __forceinline__ unsigned short f2b(float f)      // fp32->bf16 RNE
{
    union { float f; unsigned u; } x; x.f = f;
    unsigned u = x.u;
    return (unsigned short)((u + 0x7FFF + ((u >> 16) & 1)) >> 16);
}
__device__ __forceinline__ float b2f(unsigned short b)
{
    union { unsigned u; float f; } x; x.u = ((unsigned)b) << 16;
    return x.f;
}

static constexpr int NBMAX = 512;   // buckets (n<=131072)
static constexpr int ACH   = 4096;  // edges per phase-A block

// ---------------------------------------------------------------------------
// prep: all 6 weight conversions (fp32 -> padded bf16) + zero bucketCount.
// wb layout (ushort offsets): w1_lin 0..8192, w1_o1 ..12288, w1_o2 ..16384,
// w2_lin ..19456, w2_o1 ..22528, w2_o2 ..25600.
// ---------------------------------------------------------------------------
__global__ __launch_bounds__(256)
void prep_kernel(const float* __restrict__ w1_lin, const float* __restrict__ w1_o1,
                 const float* __restrict__ w1_o2, const float* __restrict__ w2_lin,
                 const float* __restrict__ w2_o1, const float* __restrict__ w2_o2,
                 unsigned short* __restrict__ wb, int* __restrict__ bucketCount)
{
    int i = blockIdx.x * 256 + threadIdx.x;
    if (i < NBMAX) bucketCount[i] = 0;
    if (i >= 25600) return;
    const float* src; int Kin, Kp, Oin, off;
    if (i < 8192)       { src = w1_lin; Kin = 128; Kp = 128; Oin = 64; off = 0; }
    else if (i < 12288) { src = w1_o1;  Kin = 64;  Kp = 64;  Oin = 64; off = 8192; }
    else if (i < 16384) { src = w1_o2;  Kin = 64;  Kp = 64;  Oin = 64; off = 12288; }
    else if (i < 19456) { src = w2_lin; Kin = 64;  Kp = 64;  Oin = 40; off = 16384; }
    else if (i < 22528) { src = w2_o1;  Kin = 40;  Kp = 64;  Oin = 40; off = 19456; }
    else                { src = w2_o2;  Kin = 40;  Kp = 64;  Oin = 40; off = 22528; }
    int j = i - off;
    int o = j / Kp, k = j - o * Kp;
    float v = (o < Oin && k < Kin) ? src[o * Kin + k] : 0.f;
    wb[i] = f2b(v);
}

// ---------------------------------------------------------------------------
// MFMA tile helper: acc[NOT] = A(16 nodes x KP) * W^T, A-frags already in regs.
// Identical index math to the verified mv kernel.
// ---------------------------------------------------------------------------
template<int NKT, int NOT>
__device__ __forceinline__ void mfma_tile(const short8* a, const unsigned short* __restrict__ Wbf,
                                          int l16, int quad, f32x4* acc)
{
    constexpr int KP = NKT * 32;
#pragma unroll
    for (int ot = 0; ot < NOT; ++ot) {
        acc[ot] = (f32x4){0.f, 0.f, 0.f, 0.f};
        const unsigned short* Wrow = Wbf + (size_t)(ot * 16 + l16) * KP + quad * 8;
#pragma unroll
        for (int kt = 0; kt < NKT; ++kt) {
            short8 b = *reinterpret_cast<const short8*>(Wrow + kt * 32);
            acc[ot] = __builtin_amdgcn_mfma_f32_16x16x32_bf16(a[kt], b, acc[ot], 0, 0, 0);
        }
    }
}

__device__ __forceinline__ short8 relu_bf16x8(short8 v)
{
#pragma unroll
    for (int j = 0; j < 8; ++j) {
        unsigned short u = (unsigned short)v[j];
        if (u & 0x8000) v[j] = 0;
    }
    return v;
}

// ---------------------------------------------------------------------------
// Fused conv1-lin (x @ W1_lin^T + b, fp32 in -> bf16 out, stride 64) + bhist.
// mv blocks: [0, tgrid). bhist blocks: [tgrid, tgrid+agrid).
// mv path is barrier-free: A-frags loaded directly from global (full-line
// coalesced: 16 rows x 128B per kt pair), per-wave independent.
// ---------------------------------------------------------------------------
__global__ __launch_bounds__(256)
void mv1_bhist_kernel(const float* __restrict__ x, const unsigned short* __restrict__ wb1_lin,
                      const float* __restrict__ b1_lin, unsigned short* __restrict__ h,
                      int n, int tgrid,
                      const int* __restrict__ dst, int* __restrict__ bucketCount, int e, int nb)
{
    __shared__ int cnt[NBMAX];
    if (blockIdx.x >= tgrid) {
        const int bb = blockIdx.x - tgrid;
        const int t = threadIdx.x;
        for (int j = t; j < nb; j += 256) cnt[j] = 0;
        __syncthreads();
        const int i0 = bb * ACH;
        const int i1 = min(e, i0 + ACH);
        for (int i = i0 + t; i < i1; i += 256)
            atomicAdd(&cnt[dst[i] >> 8], 1);
        __syncthreads();
        for (int j = t; j < nb; j += 256)
            if (cnt[j]) atomicAdd(&bucketCount[j], cnt[j]);
        return;
    }
    const int t = threadIdx.x, wave = t >> 6, lane = t & 63;
    const int quad = lane >> 4, l16 = lane & 15;
    const int n0 = blockIdx.x * 64, m0 = wave * 16;
    int row = n0 + m0 + l16; if (row >= n) row = n - 1;

    short8 a[4];
#pragma unroll
    for (int kt = 0; kt < 4; ++kt) {
        const float* p = x + (size_t)row * FIN + kt * 32 + quad * 8;
        float4 f0 = *reinterpret_cast<const float4*>(p);
        float4 f1 = *reinterpret_cast<const float4*>(p + 4);
        short8 v;
        v[0] = (short)f2b(f0.x); v[1] = (short)f2b(f0.y);
        v[2] = (short)f2b(f0.z); v[3] = (short)f2b(f0.w);
        v[4] = (short)f2b(f1.x); v[5] = (short)f2b(f1.y);
        v[6] = (short)f2b(f1.z); v[7] = (short)f2b(f1.w);
        a[kt] = v;
    }
    f32x4 acc[4];
    mfma_tile<4, 4>(a, wb1_lin, l16, quad, acc);
#pragma unroll
    for (int ot = 0; ot < 4; ++ot) {
        int o = ot * 16 + l16;
        float bv = b1_lin[o];
#pragma unroll
        for (int r = 0; r < 4; ++r) {
            int node = n0 + m0 + quad * 4 + r;
            if (node < n) h[(size_t)node * HD + o] = f2b(acc[ot][r] + bv);
        }
    }
}

// ---------------------------------------------------------------------------
// chainB: per-node dense chain between the two gathers, one kernel, 0 barriers:
//   relu(agg1) -> @W1_o1+b,relu -> @W1_o2+b -> relu -> @W2_lin+b -> bf16 [n][40]
// Per-wave 16-row LDS slab only for the acc->A-frag lane transpose.
// ---------------------------------------------------------------------------
__global__ __launch_bounds__(256)
void chainB_kernel(const unsigned short* __restrict__ agg,
                   const unsigned short* __restrict__ wo1, const float* __restrict__ bo1,
                   const unsigned short* __restrict__ wo2, const float* __restrict__ bo2,
                   const unsigned short* __restrict__ wlin, const float* __restrict__ blin,
                   unsigned short* __restrict__ out, int n)
{
    constexpr int KS = 72;                 // 64 + 8 pad (same as verified mv)
    __shared__ unsigned short lds[64 * KS];
    const int t = threadIdx.x, wave = t >> 6, lane = t & 63;
    const int quad = lane >> 4, l16 = lane & 15;
    const int n0 = blockIdx.x * 64, m0 = wave * 16;
    int row = n0 + m0 + l16; if (row >= n) row = n - 1;

    short8 a[2];
#pragma unroll
    for (int kt = 0; kt < 2; ++kt) {
        short8 v = *reinterpret_cast<const short8*>(agg + (size_t)row * HD + kt * 32 + quad * 8);
        a[kt] = relu_bf16x8(v);            // relu(agg1)
    }

    f32x4 acc[4];
    mfma_tile<2, 4>(a, wo1, l16, quad, acc);           // @W1_o1
#pragma unroll
    for (int ot = 0; ot < 4; ++ot) {
        int o = ot * 16 + l16;
        float bv = bo1[o];
#pragma unroll
        for (int r = 0; r < 4; ++r) {
            float v = fmaxf(acc[ot][r] + bv, 0.f);     // +b, relu
            lds[(m0 + quad * 4 + r) * KS + o] = f2b(v);
        }
    }
#pragma unroll
    for (int kt = 0; kt < 2; ++kt)
        a[kt] = *reinterpret_cast<const short8*>(&lds[(m0 + l16) * KS + kt * 32 + quad * 8]);

    mfma_tile<2, 4>(a, wo2, l16, quad, acc);           // @W1_o2
#pragma unroll
    for (int ot = 0; ot < 4; ++ot) {
        int o = ot * 16 + l16;
        float bv = bo2[o];
#pragma unroll
        for (int r = 0; r < 4; ++r) {
            float v = fmaxf(acc[ot][r] + bv, 0.f);     // +b, top-level relu
            lds[(m0 + quad * 4 + r) * KS + o] = f2b(v);
        }
    }
#pragma unroll
    for (int kt = 0; kt < 2; ++kt)
        a[kt] = *reinterpret_cast<const short8*>(&lds[(m0 + l16) * KS + kt * 32 + quad * 8]);

    f32x4 acc3[3];
    mfma_tile<2, 3>(a, wlin, l16, quad, acc3);         // @W2_lin (O=40, Op=48)
#pragma unroll
    for (int ot = 0; ot < 3; ++ot) {
        int o = ot * 16 + l16;
        if (o < CD) {
            float bv = blin[o];
#pragma unroll
            for (int r = 0; r < 4; ++r) {
                int node = n0 + m0 + quad * 4 + r;
                if (node < n) out[(size_t)node * CD + o] = f2b(acc3[ot][r] + bv);
            }
        }
    }
}

// ---------------------------------------------------------------------------
// chainC: relu(agg2) -> @W2_o1+b,relu -> @W2_o2+b -> fp32 out [n][40].
// ---------------------------------------------------------------------------
__global__ __launch_bounds__(256)
void chainC_kernel(const unsigned short* __restrict__ agg,
                   const unsigned short* __restrict__ wo1, const float* __restrict__ bo1,
                   const unsigned short* __restrict__ wo2, const float* __restrict__ bo2,
                   float* __restrict__ out, int n)
{
    constexpr int KS = 72;
    __shared__ unsigned short lds[64 * KS];
    const int t = threadIdx.x, wave = t >> 6, lane = t & 63;
    const int quad = lane >> 4, l16 = lane & 15;
    const int n0 = blockIdx.x * 64, m0 = wave * 16;

    // zero-pad cols 48..63 of this wave's slab (cols 40..47 written explicitly below)
    for (int i = lane; i < 16 * 16; i += 64) {
        int rr = i >> 4, cc = i & 15;
        lds[(m0 + rr) * KS + 48 + cc] = 0;
    }

    int row = n0 + m0 + l16; if (row >= n) row = n - 1;
    short8 a[2];
    {   // kt=0: cols quad*8 .. quad*8+8, all < 40
        short8 v = *reinterpret_cast<const short8*>(agg + (size_t)row * CD + quad * 8);
        a[0] = relu_bf16x8(v);
    }
    {   // kt=1: only quad 0 covers cols 32..39; quads 1..3 are zero pad
        short8 v = {0, 0, 0, 0, 0, 0, 0, 0};
        if (quad == 0) {
            v = *reinterpret_cast<const short8*>(agg + (size_t)row * CD + 32);
            v = relu_bf16x8(v);
        }
        a[1] = v;
    }

    f32x4 acc[3];
    mfma_tile<2, 3>(a, wo1, l16, quad, acc);           // @W2_o1 (Op=48)
#pragma unroll
    for (int ot = 0; ot < 3; ++ot) {
        int o = ot * 16 + l16;
        float bv = (o < CD) ? bo1[o] : 0.f;
#pragma unroll
        for (int r = 0; r < 4; ++r) {
            float v = (o < CD) ? fmaxf(acc[ot][r] + bv, 0.f) : 0.f;
            lds[(m0 + quad * 4 + r) * KS + o] = f2b(v);
        }
    }
#pragma unroll
    for (int kt = 0; kt < 2; ++kt)
        a[kt] = *reinterpret_cast<const short8*>(&lds[(m0 + l16) * KS + kt * 32 + quad * 8]);

    mfma_tile<2, 3>(a, wo2, l16, quad, acc);           // @W2_o2
#pragma unroll
    for (int ot = 0; ot < 3; ++ot) {
        int o = ot * 16 + l16;
        if (o < CD) {
            float bv = bo2[o];
#pragma unroll
            for (int r = 0; r < 4; ++r) {
                int node = n0 + m0 + quad * 4 + r;
                if (node < n) out[(size_t)node * CD + o] = acc[ot][r] + bv;
            }
        }
    }
}

// ---------------------------------------------------------------------------
// CSR build (bucketed), unchanged from verified kernel.
// ---------------------------------------------------------------------------
__global__ __launch_bounds__(256)
void bscan_kernel(const int* __restrict__ bucketCount, int* __restrict__ bucketOff,
                  int* __restrict__ bucketCursor, int nb)
{
    __shared__ int sA[NBMAX], sB[NBMAX];
    const int t = threadIdx.x;
#pragma unroll
    for (int s = t; s < NBMAX; s += 256) sA[s] = (s < nb) ? bucketCount[s] : 0;
    __syncthreads();
    int* pa = sA; int* pb = sB;
    for (int off = 1; off < NBMAX; off <<= 1) {
#pragma unroll
        for (int s = t; s < NBMAX; s += 256)
            pb[s] = pa[s] + ((s >= off) ? pa[s - off] : 0);
        __syncthreads();
        int* tmp = pa; pa = pb; pb = tmp;
    }
#pragma unroll
    for (int s = t; s <= nb && s < NBMAX; s += 256) {
        int v = (s == 0) ? 0 : pa[s - 1];
        bucketOff[s] = v;
        if (s < nb) bucketCursor[s] = v;
    }
}

__global__ __launch_bounds__(256)
void bpart_kernel(const int* __restrict__ src, const int* __restrict__ dst,
                  int* __restrict__ bucketCursor, uint2* __restrict__ pairs,
                  int e, int nb)
{
    __shared__ int cnt[NBMAX];
    __shared__ int base[NBMAX];
    const int t = threadIdx.x;
    for (int j = t; j < nb; j += 256) cnt[j] = 0;
    __syncthreads();
    const int i0 = blockIdx.x * ACH;
    const int i1 = min(e, i0 + ACH);
    for (int i = i0 + t; i < i1; i += 256)
        atomicAdd(&cnt[dst[i] >> 8], 1);
    __syncthreads();
    for (int j = t; j < nb; j += 256) {
        int c = cnt[j];
        base[j] = c ? atomicAdd(&bucketCursor[j], c) : 0;
        cnt[j] = 0;
    }
    __syncthreads();
    for (int i = i0 + t; i < i1; i += 256) {
        int d = dst[i];
        int bkt = d >> 8;
        int pos = base[bkt] + atomicAdd(&cnt[bkt], 1);
        pairs[pos] = make_uint2((unsigned)d, (unsigned)src[i]);
    }
}

__global__ __launch_bounds__(256)
void bbuild_kernel(const uint2* __restrict__ pairs, const int* __restrict__ bucketOff,
                   int* __restrict__ rowptr_end, int* __restrict__ deg_g,
                   int* __restrict__ eidx, int n)
{
    __shared__ int deg[256], sA[256], sB[256], cur[256];
    const int t = threadIdx.x;
    const int b = blockIdx.x;
    const int node0 = b << 8;
    const int e0 = bucketOff[b], e1 = bucketOff[b + 1];

    deg[t] = 0;
    __syncthreads();
    for (int i = e0 + t; i < e1; i += 256)
        atomicAdd(&deg[pairs[i].x & 255], 1);
    __syncthreads();
    sA[t] = deg[t];
    __syncthreads();
    int* pa = sA; int* pb = sB;
    for (int off = 1; off < 256; off <<= 1) {
        pb[t] = pa[t] + ((t >= off) ? pa[t - off] : 0);
        __syncthreads();
        int* tmp = pa; pa = pb; pb = tmp;
    }
    const int node = node0 + t;
    if (node < n) {
        rowptr_end[node] = e0 + pa[t];
        deg_g[node] = deg[t];
    }
    cur[t] = pa[t] - deg[t];
    __syncthreads();
    for (int i = e0 + t; i < e1; i += 256) {
        uint2 p = pairs[i];
        int pos = e0 + atomicAdd(&cur[p.x & 255], 1);
        eidx[pos] = (int)p.y;
    }
}

// ---------------------------------------------------------------------------
// Gather (bf16), unchanged from verified kernel.
// ---------------------------------------------------------------------------
template<int D>
__global__ __launch_bounds__(256)
void gather_bf16_kernel(const int* __restrict__ rowptr_end, const int* __restrict__ deg,
                        const int* __restrict__ eidx, const unsigned short* __restrict__ h,
                        unsigned short* __restrict__ agg, int n)
{
    const int wave = threadIdx.x >> 6;
    const int lane = threadIdx.x & 63;
    const int grp  = lane >> 4;
    const int l16  = lane & 15;
    const int node = blockIdx.x * 16 + wave * 4 + grp;
    const int nodec = (node < n) ? node : (n - 1);
    constexpr int LPN = D / 4;
    const bool act = (l16 < LPN) && (node < n);
    const int c0 = l16 * 4;

    float a0 = 0.f, a1 = 0.f, a2 = 0.f, a3 = 0.f;
    if (act) {
        ushort4 v = *reinterpret_cast<const ushort4*>(h + (size_t)nodec * D + c0);
        a0 = b2f(v.x); a1 = b2f(v.y); a2 = b2f(v.z); a3 = b2f(v.w);
    }
    int end   = rowptr_end[nodec];
    int start = end - deg[nodec];
    if (node >= n) end = start;

    for (int base = start; base < end; base += 16) {
        int m = min(16, end - base);
        int sv = (l16 < m) ? eidx[base + l16] : 0;
        for (int j = 0; j < m; ++j) {
            int s = __shfl(sv, grp * 16 + j, 64);
            if (act) {
                ushort4 v = *reinterpret_cast<const ushort4*>(h + (size_t)s * D + c0);
                a0 += b2f(v.x); a1 += b2f(v.y); a2 += b2f(v.z); a3 += b2f(v.w);
            }
        }
    }
    if (act) {
        ushort4 o;
        o.x = f2b(a0); o.y = f2b(a1); o.z = f2b(a2); o.w = f2b(a3);
        *reinterpret_cast<ushort4*>(agg + (size_t)node * D + c0) = o;
    }
}

extern "C" void kernel_launch(void* const* d_in, const int* in_sizes, int n_in,
                              void* d_out, int out_size, void* d_ws, size_t ws_size,
                              hipStream_t stream)
{
    const float* x      = (const float*)d_in[0];
    const int*   ei     = (const int*)d_in[1];
    const float* w1_lin = (const float*)d_in[2];
    const float* b1_lin = (const float*)d_in[3];
    const float* w1_o1  = (const float*)d_in[4];
    const float* b1_o1  = (const float*)d_in[5];
    const float* w1_o2  = (const float*)d_in[6];
    const float* b1_o2  = (const float*)d_in[7];
    const float* w2_lin = (const float*)d_in[8];
    const float* b2_lin = (const float*)d_in[9];
    const float* w2_o1  = (const float*)d_in[10];
    const float* b2_o1  = (const float*)d_in[11];
    const float* w2_o2  = (const float*)d_in[12];
    const float* b2_o2  = (const float*)d_in[13];

    const int n = in_sizes[0] / FIN;   // 100000
    const int e = in_sizes[1] / 2;     // 1000000
    const int* src = ei;
    const int* dst = ei + e;

    // ---- d_ws layout ----
    unsigned short* ws0 = (unsigned short*)d_ws;
    unsigned short* ws1 = ws0 + (size_t)n * HD;
    unsigned short* wb  = ws1 + (size_t)n * HD;
    unsigned short* wb1_lin = wb;                 // [64][128]
    unsigned short* wb1_o1  = wb1_lin + 64 * 128; // [64][64]
    unsigned short* wb1_o2  = wb1_o1  + 64 * 64;  // [64][64]
    unsigned short* wb2_lin = wb1_o2  + 64 * 64;  // [48][64]
    unsigned short* wb2_o1  = wb2_lin + 48 * 64;  // [48][64]
    unsigned short* wb2_o2  = wb2_o1  + 48 * 64;  // [48][64]
    uint2* pairs        = (uint2*)(wb2_o2 + 48 * 64);
    int*   bucketCount  = (int*)(pairs + e);
    int*   bucketOff    = bucketCount + NBMAX;
    int*   bucketCursor = bucketOff + NBMAX + 1;
    float* outp = (float*)d_out;

    // CSR arrays in d_out (consumed by gathers before chainC writes d_out).
    int* eidx   = (int*)d_out;
    int* deg    = eidx + e;
    int* rowptr = deg + n;

    const int nb    = (n + 255) >> 8;             // 391 buckets
    const int agrid = (e + ACH - 1) / ACH;        // 245 blocks
    const int tgrid = (n + 63) / 64;              // 1563 blocks
    const int ggrid = (n + 15) / 16;              // 6250 blocks

    // 1. weights + bucketCount zero (one kernel, replaces 6 wconv + memset)
    prep_kernel<<<(25600 + 255) / 256, 256, 0, stream>>>(
        w1_lin, w1_o1, w1_o2, w2_lin, w2_o1, w2_o2, wb, bucketCount);

    // 2. conv1-lin mv + bhist fused (independent work, one dispatch)
    mv1_bhist_kernel<<<tgrid + agrid, 256, 0, stream>>>(
        x, wb1_lin, b1_lin, ws0, n, tgrid, dst, bucketCount, e, nb);

    // 3-5. CSR build
    bscan_kernel<<<1, 256, 0, stream>>>(bucketCount, bucketOff, bucketCursor, nb);
    bpart_kernel<<<agrid, 256, 0, stream>>>(src, dst, bucketCursor, pairs, e, nb);
    bbuild_kernel<<<nb, 256, 0, stream>>>(pairs, bucketOff, rowptr, deg, eidx, n);

    // 6. gather1 (agg1 = sum_neighbors h + h)
    gather_bf16_kernel<HD><<<ggrid, 256, 0, stream>>>(rowptr, deg, eidx, ws0, ws1, n);

    // 7. fused chain: relu -> W1_o1+relu -> W1_o2 -> relu -> W2_lin  (3 mv in 1)
    chainB_kernel<<<tgrid, 256, 0, stream>>>(
        ws1, wb1_o1, b1_o1, wb1_o2, b1_o2, wb2_lin, b2_lin, ws0, n);

    // 8. gather2
    gather_bf16_kernel<CD><<<ggrid, 256, 0, stream>>>(rowptr, deg, eidx, ws0, ws1, n);

    // 9. fused chain: relu -> W2_o1+relu -> W2_o2 -> out fp32  (2 mv in 1)
    chainC_kernel<<<tgrid, 256, 0, stream>>>(
        ws1, wb2_o1, b2_o1, wb2_o2, b2_o2, outp, n);
}